// Round 9
// baseline (21.010 us; speedup 1.0000x reference)
//
#include <hip/hip_runtime.h>

__device__ __forceinline__ float frcp(float x) { return __builtin_amdgcn_rcpf(x); }

typedef float f32x4 __attribute__((ext_vector_type(4)));

#define ROWS 256                      // rows per block (= blockDim.x)
#define WROWS 64                      // rows per wave
#define WAVE_F4 (WROWS * 10 / 4)      // 160 float4 chunks staged per wave

// Wave-synchronous: each wave owns a private 2560 B LDS slice; no __syncthreads.
// DS ops from one wave complete in order; lgkmcnt(0) + "memory" clobber enforce
// the write->read ordering against both HW counters and compiler motion.
__global__ __launch_bounds__(256) void amber_dyn_wsync(
    const f32x4* __restrict__ st4,   // state as float4 stream [B*10/4]
    const f32x4* __restrict__ u4,    // [B]
    f32x4* __restrict__ out4,        // [B*10/4]
    int B)
{
    __shared__ float lds[ROWS * 10];            // 10240 B (4 waves x 2560 B)

    const int tid  = threadIdx.x;
    const int wid  = tid >> 6;
    const int lane = tid & 63;

    float*  wlds  = lds + wid * (WROWS * 10);   // this wave's slice
    f32x4*  wlds4 = reinterpret_cast<f32x4*>(wlds);

    const int wrow0   = blockIdx.x * ROWS + wid * WROWS; // wave's first row
    const int f4base  = wrow0 * 10 / 4;                  // wrow0 % 4 == 0
    const int totalF4 = B * 10 / 4;
    const int row     = wrow0 + lane;

    // hoist u load; latency hides under staging
    f32x4 uv = {0.f, 0.f, 0.f, 0.f};
    if (row < B) uv = u4[row];

    // ---- stage 1: coalesced global b128 -> this wave's LDS slice ----
    #pragma unroll
    for (int it = 0; it < 3; ++it) {
        int i = lane + it * 64;
        if (i < WAVE_F4) {
            int g = f4base + i;
            if (g < totalF4) wlds4[i] = st4[g];
        }
    }
    asm volatile("s_waitcnt lgkmcnt(0)" ::: "memory");   // wave-local sync

    // ---- stage 2: per-lane row compute (own row only, in place) ----
    if (row < B) {
        float* myrow = wlds + lane * 10;
        float q[5], qd[5];
        #pragma unroll
        for (int i = 0; i < 5; ++i) { q[i] = myrow[i]; qd[i] = myrow[5 + i]; }

        float s[5], c[5];
        #pragma unroll
        for (int i = 0; i < 5; ++i) __sincosf(q[i], &s[i], &c[i]);

        float v2 = qd[0]*qd[0] + qd[1]*qd[1] + qd[2]*qd[2] + qd[3]*qd[3] + qd[4]*qd[4];
        float coef = 0.1f * v2 + 9.8f;

        float bu[5] = {0.f, uv.x, uv.y, uv.z, uv.w};
        float r[5];
        #pragma unroll
        for (int i = 0; i < 5; ++i)
            r[i] = bu[i] - (coef * s[i] + 0.05f * qd[i]);

        // Woodbury: D = 2I + 0.3(cc^T+ss^T);
        // D^-1 r = 0.5 r - 0.25 U M^-1 U^T r,  M = (10/3)I + 0.5 U^T U
        float cc = 0.f, cs = 0.f, pc = 0.f, ps = 0.f;
        #pragma unroll
        for (int i = 0; i < 5; ++i) {
            cc += c[i]*c[i]; cs += c[i]*s[i];
            pc += c[i]*r[i]; ps += s[i]*r[i];
        }
        float ss = 5.0f - cc;                   // ci^2+si^2 = 1

        const float K = 10.0f / 3.0f;
        float m00 = K + 0.5f * cc;
        float m01 = 0.5f * cs;
        float m11 = K + 0.5f * ss;

        float idet = frcp(m00 * m11 - m01 * m01);
        float y0 = 0.25f * idet * (m11 * pc - m01 * ps);
        float y1 = 0.25f * idet * (m00 * ps - m01 * pc);

        #pragma unroll
        for (int i = 0; i < 5; ++i) {
            myrow[i]     = qd[i];
            myrow[5 + i] = 0.5f * r[i] - (c[i] * y0 + s[i] * y1);
        }
    }
    asm volatile("s_waitcnt lgkmcnt(0)" ::: "memory");   // wave-local sync

    // ---- stage 3: this wave's LDS slice -> coalesced global b128 ----
    #pragma unroll
    for (int it = 0; it < 3; ++it) {
        int i = lane + it * 64;
        if (i < WAVE_F4) {
            int g = f4base + i;
            if (g < totalF4) out4[g] = wlds4[i];
        }
    }
}

extern "C" void kernel_launch(void* const* d_in, const int* in_sizes, int n_in,
                              void* d_out, int out_size, void* d_ws, size_t ws_size,
                              hipStream_t stream) {
    // inputs (setup_inputs order): t [1], state [B*10], u [B*4]
    const float* state = (const float*)d_in[1];
    const float* u     = (const float*)d_in[2];
    float* out = (float*)d_out;
    int B = in_sizes[1] / 10;

    int grid = (B + ROWS - 1) / ROWS;
    amber_dyn_wsync<<<grid, ROWS, 0, stream>>>(
        (const f32x4*)state, (const f32x4*)u, (f32x4*)out, B);
}